// Round 8
// baseline (64.626 us; speedup 1.0000x reference)
//
#include <hip/hip_runtime.h>
#include <hip/hip_bf16.h>

#define B_ 32
#define L_ 2048
#define E_ 256
#define H_ 256
#define MAXSTEP 20
#define NLW 4     // l's per 1-wave block
#define NCH 26    // ceil(103/NLW)

typedef __attribute__((ext_vector_type(4))) float f32x4;
typedef __attribute__((ext_vector_type(8))) short bf16x8;
using bf16 = __hip_bfloat16;

__device__ inline short cvt1(float x) {
    bf16 b = __float2bfloat16(x);
    return *reinterpret_cast<short*>(&b);
}

// Transpose + convert: cnn fp32 [s][e][h] -> wt bf16 [s][h][e] (K-contiguous B operand).
__global__ void transpose_w_kernel(const float* __restrict__ cnn, short* __restrict__ wt) {
    __shared__ short tile[32][33];
    const int s  = blockIdx.z;
    const int e0 = blockIdx.y * 32;
    const int h0 = blockIdx.x * 32;
    const int tx = threadIdx.x;
    const int ty = threadIdx.y;
    const float* src = cnn + ((size_t)s * E_ + e0) * H_ + h0;
#pragma unroll
    for (int i = ty; i < 32; i += 8)
        tile[i][tx] = cvt1(src[(size_t)i * H_ + tx]);
    __syncthreads();
    short* dst = wt + ((size_t)s * H_ + h0) * E_ + e0;
#pragma unroll
    for (int i = ty; i < 32; i += 8)
        dst[(size_t)i * E_ + tx] = tile[tx][i];
}

// out2 = out[:, L-1, :]  (separate kernel keeps main-kernel store counts uniform)
__global__ void copy_last_kernel(const float* __restrict__ out, float* __restrict__ out2) {
    const int h = threadIdx.x;               // 0..255
#pragma unroll
    for (int b = 0; b < B_; ++b)
        out2[(size_t)b * H_ + h] = out[((size_t)b * L_ + (L_ - 1)) * H_ + h];
}

// Barrier-free 1-wave blocks. Block = (s, chunk, colgroup): one 64-lane wave
// computes out[0:32, l, cg*64:(cg+1)*64] for NLW same-s l's. B (W^T[s], 64
// h-rows) in 128 VGPRs. A staged per-wave: quarter-K sub-tiles (32 rows x 64 k
// fp32 = 8 KB) via global_load_lds into 3 private LDS buffers, 2 tiles ahead.
// NO s_barrier anywhere — each wave orders its own DMA with in-order vmcnt.
// Per-tile vmem stream: 8 stage ops; 32 stores at q==3. In-order queue at the
// wait of tile t=il*4+q (stage(t) issued at start of t-2):
//   il=0,q0: [breg:32|s0:8|s1:8|s2:8]      -> vmcnt(16)
//   il=0,q1: [s1|s2|s3]                    -> vmcnt(16)
//   q0(il>0): [s(t)|s(t+1)|ST:32|s(t+2)]   -> vmcnt(48)
//   q1(il>0): [s(t)|ST:32|s(t+1)|s(t+2)]   -> vmcnt(48)
//   q2: [ST?|s(t)|s(t+1)|s(t+2)]           -> vmcnt(16)  (ST had >=1.5 tiles)
//   q3: [ST?|s(t)|s(t+1)|s(t+2)]           -> vmcnt(16)
//   last il: q2 -> vmcnt(8), q3 -> vmcnt(0) (no t+2 stages issued)
// LDS source-swizzle: LDS[row][c] holds global chunk c^(row&7) (16B chunks);
// reads use the same XOR. mfma_f32_16x16x32_bf16 layouts as before.
__global__ __launch_bounds__(64, 2) void vaw_wave_kernel(
        const float* __restrict__ A, const short* __restrict__ Wt,
        float* __restrict__ out) {
    __shared__ __align__(16) float aLds[3][B_ * 64];   // 3 x 8 KB, wave-private

    const int bid   = blockIdx.x;
    const int cg    = bid & 3;                 // column group
    const int sc    = bid >> 2;
    const int s     = sc / NCH;
    const int chunk = sc % NCH;
    const int cnt   = (s < 8) ? 103 : 102;     // #{l < 2048 : l % 20 == s}
    const int lane  = threadIdx.x;             // 0..63
    const int r     = lane & 15;
    const int g     = lane >> 4;
    const int nbase = cg * 64;
    const int key   = r & 7;

    // ---- B into registers: breg[kk][nf], 32 x 16B loads (L2/L3-resident Wt).
    const short* wtb = Wt + ((size_t)s * H_ + nbase + r) * E_ + g * 8;
    bf16x8 breg[8][4];
#pragma unroll
    for (int kk = 0; kk < 8; ++kk)
#pragma unroll
        for (int nf = 0; nf < 4; ++nf)
            breg[kk][nf] = *(const bf16x8*)(wtb + (size_t)nf * 16 * E_ + kk * 32);

    auto lof = [&](int il) {
        int idx = chunk * NLW + il;
        if (idx > cnt - 1) idx = cnt - 1;      // tail clamp: duplicate work, benign
        return s + 20 * idx;
    };

    // Stage sub-tile td (l = lof(td>>2), k-quarter td&3) into aLds[td%3].
    // 8 instrs x 1 KB; instr j covers rows 4j..4j+3 linearly in LDS; lane
    // covers (row = 4j + lane/16, chunk = lane%16); global chunk = chunk^(row&7).
    auto stage = [&](int td) {
        const int l  = lof(td >> 2);
        const int kq = td & 3;
        float* dst = aLds[td % 3];
        const int row = (lane >> 4);           // 0..3 within the 4-row group
        const int cL  = lane & 15;
#pragma unroll
        for (int j = 0; j < 8; ++j) {
            const int rr = j * 4 + row;
            const int cG = cL ^ (rr & 7);
            const float* gp = A + ((size_t)rr * L_ + l) * E_ + kq * 64 + cG * 4;
            __builtin_amdgcn_global_load_lds(
                (const __attribute__((address_space(1))) void*)gp,
                (__attribute__((address_space(3))) void*)&dst[j * 4 * 64],
                16, 0, 0);
        }
    };

    stage(0);
    stage(1);

    f32x4 acc[2][4];

#pragma unroll 1
    for (int il = 0; il < NLW; ++il) {
        const int l     = lof(il);
        const bool first = (il == 0);
        const bool last  = (il == NLW - 1);

#pragma unroll
        for (int q = 0; q < 4; ++q) {
            const int t   = il * 4 + q;
            const int buf = t % 3;

            if (!last || q < 2) stage(t + 2);

            if (q == 0) {
                if (first) asm volatile("s_waitcnt vmcnt(16)" ::: "memory");
                else       asm volatile("s_waitcnt vmcnt(48)" ::: "memory");
            } else if (q == 1) {
                if (first) asm volatile("s_waitcnt vmcnt(16)" ::: "memory");
                else       asm volatile("s_waitcnt vmcnt(48)" ::: "memory");
            } else if (q == 2) {
                if (last)  asm volatile("s_waitcnt vmcnt(8)"  ::: "memory");
                else       asm volatile("s_waitcnt vmcnt(16)" ::: "memory");
            } else {
                if (last)  asm volatile("s_waitcnt vmcnt(0)"  ::: "memory");
                else       asm volatile("s_waitcnt vmcnt(16)" ::: "memory");
            }
            __builtin_amdgcn_sched_barrier(0);

            if (q == 0) {
#pragma unroll
                for (int mf = 0; mf < 2; ++mf)
#pragma unroll
                    for (int nf = 0; nf < 4; ++nf)
                        acc[mf][nf] = f32x4{0.f, 0.f, 0.f, 0.f};
            }

#pragma unroll
            for (int kkh = 0; kkh < 2; ++kkh) {
                const int kk = q * 2 + kkh;
                const int c0 = kkh * 8 + g * 2;
                f32x4 a0lo = *(const f32x4*)&aLds[buf][r * 64 + ((c0 ^ key) << 2)];
                f32x4 a0hi = *(const f32x4*)&aLds[buf][r * 64 + (((c0 + 1) ^ key) << 2)];
                f32x4 a1lo = *(const f32x4*)&aLds[buf][(r + 16) * 64 + ((c0 ^ key) << 2)];
                f32x4 a1hi = *(const f32x4*)&aLds[buf][(r + 16) * 64 + (((c0 + 1) ^ key) << 2)];
                bf16x8 a0, a1;
#pragma unroll
                for (int j = 0; j < 4; ++j) {
                    a0[j]     = cvt1(a0lo[j]);
                    a0[j + 4] = cvt1(a0hi[j]);
                    a1[j]     = cvt1(a1lo[j]);
                    a1[j + 4] = cvt1(a1hi[j]);
                }
#pragma unroll
                for (int nf = 0; nf < 4; ++nf) {
                    acc[0][nf] = __builtin_amdgcn_mfma_f32_16x16x32_bf16(a0, breg[kk][nf], acc[0][nf], 0, 0, 0);
                    acc[1][nf] = __builtin_amdgcn_mfma_f32_16x16x32_bf16(a1, breg[kk][nf], acc[1][nf], 0, 0, 0);
                }
            }

            if (q == 3) {
                const int row0 = g * 4;
#pragma unroll
                for (int mf = 0; mf < 2; ++mf) {
#pragma unroll
                    for (int nf = 0; nf < 4; ++nf) {
                        const int h = nbase + nf * 16 + r;
#pragma unroll
                        for (int i = 0; i < 4; ++i) {
                            const int bb = mf * 16 + row0 + i;
                            out[((size_t)bb * L_ + l) * H_ + h] = acc[mf][nf][i];
                        }
                    }
                }
            }
        }
    }
}

// Fallback (no workspace): round-5 structure, B from fp32 cnn per k-step.
__global__ __launch_bounds__(256) void vaw_fallback_kernel(
        const float* __restrict__ A, const float* __restrict__ W, float* __restrict__ out) {
    __shared__ __align__(16) float aLds[2][B_ * E_];
    const int l0   = blockIdx.x * 4;
    const int wv   = threadIdx.x >> 6;
    const int lane = threadIdx.x & 63;
    const int r    = lane & 15;
    const int g    = lane >> 4;
    const int nbase = wv * 64;
    const int key   = r & 7;

    auto stage = [&](int it) {
        float* dst = aLds[it & 1];
        const int l = l0 + it;
#pragma unroll
        for (int t = 0; t < 8; ++t) {
            const int b  = t * 4 + wv;
            const int cgx = lane ^ (b & 7);
            const float* gp = A + ((size_t)b * L_ + l) * E_ + cgx * 4;
            __builtin_amdgcn_global_load_lds(
                (const __attribute__((address_space(1))) void*)gp,
                (__attribute__((address_space(3))) void*)&dst[b * 256],
                16, 0, 0);
        }
    };

    stage(0);
#pragma unroll 1
    for (int it = 0; it < 4; ++it) {
        const int l   = l0 + it;
        const int sidx = l % MAXSTEP;
        const int cur = it & 1;
        if (it < 3) {
            stage(it + 1);
            asm volatile("s_waitcnt vmcnt(8)" ::: "memory");
        } else {
            asm volatile("s_waitcnt vmcnt(0)" ::: "memory");
        }
        __builtin_amdgcn_s_barrier();
        __builtin_amdgcn_sched_barrier(0);

        f32x4 acc[2][4] = {};
        const float* Wf = W + (size_t)sidx * E_ * H_;
#pragma unroll 2
        for (int kk = 0; kk < 8; ++kk) {
            const int k0 = kk * 32;
            const int c0 = kk * 8 + g * 2;
            f32x4 a0lo = *(const f32x4*)&aLds[cur][r * 256 + ((c0 ^ key) << 2)];
            f32x4 a0hi = *(const f32x4*)&aLds[cur][r * 256 + (((c0 + 1) ^ key) << 2)];
            f32x4 a1lo = *(const f32x4*)&aLds[cur][(r + 16) * 256 + ((c0 ^ key) << 2)];
            f32x4 a1hi = *(const f32x4*)&aLds[cur][(r + 16) * 256 + (((c0 + 1) ^ key) << 2)];
            bf16x8 a0, a1;
#pragma unroll
            for (int j = 0; j < 4; ++j) {
                a0[j]     = cvt1(a0lo[j]);
                a0[j + 4] = cvt1(a0hi[j]);
                a1[j]     = cvt1(a1lo[j]);
                a1[j + 4] = cvt1(a1hi[j]);
            }
            bf16x8 b0, b1, b2, b3;
#pragma unroll
            for (int j = 0; j < 8; ++j) {
                const size_t krow = (size_t)(k0 + g * 8 + j) * H_;
                b0[j] = cvt1(Wf[krow + nbase +  0 + r]);
                b1[j] = cvt1(Wf[krow + nbase + 16 + r]);
                b2[j] = cvt1(Wf[krow + nbase + 32 + r]);
                b3[j] = cvt1(Wf[krow + nbase + 48 + r]);
            }
            acc[0][0] = __builtin_amdgcn_mfma_f32_16x16x32_bf16(a0, b0, acc[0][0], 0, 0, 0);
            acc[0][1] = __builtin_amdgcn_mfma_f32_16x16x32_bf16(a0, b1, acc[0][1], 0, 0, 0);
            acc[0][2] = __builtin_amdgcn_mfma_f32_16x16x32_bf16(a0, b2, acc[0][2], 0, 0, 0);
            acc[0][3] = __builtin_amdgcn_mfma_f32_16x16x32_bf16(a0, b3, acc[0][3], 0, 0, 0);
            acc[1][0] = __builtin_amdgcn_mfma_f32_16x16x32_bf16(a1, b0, acc[1][0], 0, 0, 0);
            acc[1][1] = __builtin_amdgcn_mfma_f32_16x16x32_bf16(a1, b1, acc[1][1], 0, 0, 0);
            acc[1][2] = __builtin_amdgcn_mfma_f32_16x16x32_bf16(a1, b2, acc[1][2], 0, 0, 0);
            acc[1][3] = __builtin_amdgcn_mfma_f32_16x16x32_bf16(a1, b3, acc[1][3], 0, 0, 0);
        }

        const int row0 = g * 4;
#pragma unroll
        for (int mf = 0; mf < 2; ++mf)
#pragma unroll
            for (int nf = 0; nf < 4; ++nf) {
                const int h = nbase + nf * 16 + r;
#pragma unroll
                for (int i = 0; i < 4; ++i) {
                    const int bb = mf * 16 + row0 + i;
                    out[((size_t)bb * L_ + l) * H_ + h] = acc[mf][nf][i];
                }
            }
        if (l == L_ - 1) {
            float* out2 = out + (size_t)B_ * L_ * H_;
#pragma unroll
            for (int mf = 0; mf < 2; ++mf)
#pragma unroll
                for (int nf = 0; nf < 4; ++nf) {
                    const int h = nbase + nf * 16 + r;
#pragma unroll
                    for (int i = 0; i < 4; ++i) {
                        const int bb = mf * 16 + row0 + i;
                        out2[(size_t)bb * H_ + h] = acc[mf][nf][i];
                    }
                }
        }
        __builtin_amdgcn_s_barrier();
    }
}

extern "C" void kernel_launch(void* const* d_in, const int* in_sizes, int n_in,
                              void* d_out, int out_size, void* d_ws, size_t ws_size,
                              hipStream_t stream) {
    const float* word_rep = (const float*)d_in[0];
    const float* cnn      = (const float*)d_in[1];
    float* out = (float*)d_out;

    const size_t wt_bytes = (size_t)MAXSTEP * E_ * H_ * sizeof(short);
    if (ws_size >= wt_bytes) {
        short* wt = (short*)d_ws;
        transpose_w_kernel<<<dim3(8, 8, 20), dim3(32, 8), 0, stream>>>(cnn, wt);
        vaw_wave_kernel<<<dim3(MAXSTEP * NCH * 4), dim3(64), 0, stream>>>(word_rep, wt, out);
        copy_last_kernel<<<dim3(1), dim3(256), 0, stream>>>(out, out + (size_t)B_ * L_ * H_);
    } else {
        vaw_fallback_kernel<<<dim3(L_ / 4), dim3(256), 0, stream>>>(word_rep, cnn, out);
    }
}

// Round 9
// 45.492 us; speedup vs baseline: 1.4206x; 1.4206x over previous
//
#include <hip/hip_runtime.h>
#include <hip/hip_bf16.h>

#define B_ 32
#define L_ 2048
#define E_ 256
#define H_ 256
#define MAXSTEP 20
#define NLW 4     // l's per 1-wave block
#define NCH 26    // ceil(103/NLW)
#define NGRP (MAXSTEP * NCH)   // 520 (s,chunk) groups; x4 column groups = 2080 blocks

typedef __attribute__((ext_vector_type(4))) float f32x4;
typedef __attribute__((ext_vector_type(8))) short bf16x8;
using bf16 = __hip_bfloat16;

__device__ inline short cvt1(float x) {
    bf16 b = __float2bfloat16(x);
    return *reinterpret_cast<short*>(&b);
}

// Transpose + convert: cnn fp32 [s][e][h] -> wt bf16 [s][h][e] (K-contiguous B operand).
__global__ void transpose_w_kernel(const float* __restrict__ cnn, short* __restrict__ wt) {
    __shared__ short tile[32][33];
    const int s  = blockIdx.z;
    const int e0 = blockIdx.y * 32;
    const int h0 = blockIdx.x * 32;
    const int tx = threadIdx.x;
    const int ty = threadIdx.y;
    const float* src = cnn + ((size_t)s * E_ + e0) * H_ + h0;
#pragma unroll
    for (int i = ty; i < 32; i += 8)
        tile[i][tx] = cvt1(src[(size_t)i * H_ + tx]);
    __syncthreads();
    short* dst = wt + ((size_t)s * H_ + h0) * E_ + e0;
#pragma unroll
    for (int i = ty; i < 32; i += 8)
        dst[(size_t)i * E_ + tx] = tile[tx][i];
}

// Barrier-free 1-wave blocks + XCD co-location. Physical block id p:
//   xcd = p%8, slot = p/8, group g = xcd + 8*(slot/4), colgroup cg = slot%4.
// All 4 cg-siblings of group g share p%8 -> same XCD -> A-tile staged by the
// first sibling is L2-hit for the other three (FETCH_SIZE ~= A read once).
// One wave computes out[0:32, l, cg*64:(cg+1)*64] for NLW same-s l's.
// B (W^T[s], 64 h-rows) in 128 VGPRs. A staged per-wave: quarter-K sub-tiles
// (32 rows x 64 k fp32 = 8 KB) via global_load_lds into 3 private LDS buffers,
// 2 tiles ahead; ordering by in-order vmcnt only (no s_barrier).
// Queue at wait of tile t (stage=8 ops, ST=32 stores after q3; breg=32 ops
// issued after stage(0),stage(1)):
//   t=0: [s0|s1|breg|s2]          -> vmcnt(48)
//   t=1: [s1|breg|s2|s3]          -> vmcnt(48)
//   t=2,3 (il=0): [s(t)|s(t+1)|s(t+2)] -> vmcnt(16)   (breg drained by MFMA use)
//   il>0: q0/q1: [s(t)|...|ST|...|s(t+2)] -> vmcnt(48); q2/q3 -> vmcnt(16)
//   last il: q2 -> vmcnt(8), q3 -> vmcnt(0)
// (The l==2047 block issues 32 extra out2 stores in one epilogue; extra queue
//  entries only cause over-waits there — still correct.)
// LDS source-swizzle: LDS[row][c] holds global chunk c^(row&7) (16B chunks);
// reads use the same XOR. mfma_f32_16x16x32_bf16: A row=lane&15,
// k=(lane>>4)*8+j; B col=lane&15; C/D col=lane&15, row=(lane>>4)*4+reg.
__global__ __launch_bounds__(64, 4) void vaw_wave_kernel(
        const float* __restrict__ A, const short* __restrict__ Wt,
        float* __restrict__ out) {
    __shared__ __align__(16) float aLds[3][B_ * 64];   // 3 x 8 KB, wave-private

    const int p     = blockIdx.x;
    const int xcd   = p & 7;
    const int slot  = p >> 3;
    const int g_    = xcd + 8 * (slot >> 2);   // group in [0,520)
    const int cg    = slot & 3;                // column group
    const int s     = g_ / NCH;
    const int chunk = g_ % NCH;
    const int cnt   = (s < 8) ? 103 : 102;     // #{l < 2048 : l % 20 == s}
    const int lane  = threadIdx.x;             // 0..63
    const int r     = lane & 15;
    const int g     = lane >> 4;
    const int nbase = cg * 64;
    const int key   = r & 7;

    auto lof = [&](int il) {
        int idx = chunk * NLW + il;
        if (idx > cnt - 1) idx = cnt - 1;      // tail clamp: duplicate work, benign
        return s + 20 * idx;
    };

    // Stage sub-tile td (l = lof(td>>2), k-quarter td&3) into aLds[td%3].
    // 8 instrs x 1 KB; instr j covers rows 4j..4j+3 linearly in LDS; lane
    // covers (row = 4j + lane/16, chunk = lane%16); global chunk = chunk^(row&7).
    auto stage = [&](int td) {
        const int l  = lof(td >> 2);
        const int kq = td & 3;
        float* dst = aLds[td % 3];
        const int row = (lane >> 4);           // 0..3 within the 4-row group
        const int cL  = lane & 15;
#pragma unroll
        for (int j = 0; j < 8; ++j) {
            const int rr = j * 4 + row;
            const int cG = cL ^ (rr & 7);
            const float* gp = A + ((size_t)rr * L_ + l) * E_ + kq * 64 + cG * 4;
            __builtin_amdgcn_global_load_lds(
                (const __attribute__((address_space(1))) void*)gp,
                (__attribute__((address_space(3))) void*)&dst[j * 4 * 64],
                16, 0, 0);
        }
    };

    stage(0);
    stage(1);

    // ---- B into registers: breg[kk][nf], 32 x 16B loads (L2/L3-resident Wt).
    const short* wtb = Wt + ((size_t)s * H_ + nbase + r) * E_ + g * 8;
    bf16x8 breg[8][4];
#pragma unroll
    for (int kk = 0; kk < 8; ++kk)
#pragma unroll
        for (int nf = 0; nf < 4; ++nf)
            breg[kk][nf] = *(const bf16x8*)(wtb + (size_t)nf * 16 * E_ + kk * 32);

    f32x4 acc[2][4];

#pragma unroll 1
    for (int il = 0; il < NLW; ++il) {
        const int l      = lof(il);
        const bool first = (il == 0);
        const bool last  = (il == NLW - 1);

#pragma unroll
        for (int q = 0; q < 4; ++q) {
            const int t   = il * 4 + q;
            const int buf = t % 3;

            if (!last || q < 2) stage(t + 2);

            if (q == 0) {
                asm volatile("s_waitcnt vmcnt(48)" ::: "memory");
            } else if (q == 1) {
                asm volatile("s_waitcnt vmcnt(48)" ::: "memory");
            } else if (q == 2) {
                if (last)  asm volatile("s_waitcnt vmcnt(8)"  ::: "memory");
                else       asm volatile("s_waitcnt vmcnt(16)" ::: "memory");
            } else {
                if (last)  asm volatile("s_waitcnt vmcnt(0)"  ::: "memory");
                else       asm volatile("s_waitcnt vmcnt(16)" ::: "memory");
            }
            __builtin_amdgcn_sched_barrier(0);

            if (q == 0) {
#pragma unroll
                for (int mf = 0; mf < 2; ++mf)
#pragma unroll
                    for (int nf = 0; nf < 4; ++nf)
                        acc[mf][nf] = f32x4{0.f, 0.f, 0.f, 0.f};
            }

#pragma unroll
            for (int kkh = 0; kkh < 2; ++kkh) {
                const int kk = q * 2 + kkh;
                const int c0 = kkh * 8 + g * 2;
                f32x4 a0lo = *(const f32x4*)&aLds[buf][r * 64 + ((c0 ^ key) << 2)];
                f32x4 a0hi = *(const f32x4*)&aLds[buf][r * 64 + (((c0 + 1) ^ key) << 2)];
                f32x4 a1lo = *(const f32x4*)&aLds[buf][(r + 16) * 64 + ((c0 ^ key) << 2)];
                f32x4 a1hi = *(const f32x4*)&aLds[buf][(r + 16) * 64 + (((c0 + 1) ^ key) << 2)];
                bf16x8 a0, a1;
#pragma unroll
                for (int j = 0; j < 4; ++j) {
                    a0[j]     = cvt1(a0lo[j]);
                    a0[j + 4] = cvt1(a0hi[j]);
                    a1[j]     = cvt1(a1lo[j]);
                    a1[j + 4] = cvt1(a1hi[j]);
                }
#pragma unroll
                for (int nf = 0; nf < 4; ++nf) {
                    acc[0][nf] = __builtin_amdgcn_mfma_f32_16x16x32_bf16(a0, breg[kk][nf], acc[0][nf], 0, 0, 0);
                    acc[1][nf] = __builtin_amdgcn_mfma_f32_16x16x32_bf16(a1, breg[kk][nf], acc[1][nf], 0, 0, 0);
                }
            }

            if (q == 3) {
                const int row0 = g * 4;
#pragma unroll
                for (int mf = 0; mf < 2; ++mf) {
#pragma unroll
                    for (int nf = 0; nf < 4; ++nf) {
                        const int h = nbase + nf * 16 + r;
#pragma unroll
                        for (int i = 0; i < 4; ++i) {
                            const int bb = mf * 16 + row0 + i;
                            out[((size_t)bb * L_ + l) * H_ + h] = acc[mf][nf][i];
                        }
                    }
                }
                if (l == L_ - 1) {
                    float* out2 = out + (size_t)B_ * L_ * H_;
#pragma unroll
                    for (int mf = 0; mf < 2; ++mf)
#pragma unroll
                        for (int nf = 0; nf < 4; ++nf) {
                            const int h = nbase + nf * 16 + r;
#pragma unroll
                            for (int i = 0; i < 4; ++i) {
                                const int bb = mf * 16 + row0 + i;
                                out2[(size_t)bb * H_ + h] = acc[mf][nf][i];
                            }
                        }
                }
            }
        }
    }
}

// Fallback (no workspace): round-5 structure, B from fp32 cnn per k-step.
__global__ __launch_bounds__(256) void vaw_fallback_kernel(
        const float* __restrict__ A, const float* __restrict__ W, float* __restrict__ out) {
    __shared__ __align__(16) float aLds[2][B_ * E_];
    const int l0   = blockIdx.x * 4;
    const int wv   = threadIdx.x >> 6;
    const int lane = threadIdx.x & 63;
    const int r    = lane & 15;
    const int g    = lane >> 4;
    const int nbase = wv * 64;
    const int key   = r & 7;

    auto stage = [&](int it) {
        float* dst = aLds[it & 1];
        const int l = l0 + it;
#pragma unroll
        for (int t = 0; t < 8; ++t) {
            const int b  = t * 4 + wv;
            const int cgx = lane ^ (b & 7);
            const float* gp = A + ((size_t)b * L_ + l) * E_ + cgx * 4;
            __builtin_amdgcn_global_load_lds(
                (const __attribute__((address_space(1))) void*)gp,
                (__attribute__((address_space(3))) void*)&dst[b * 256],
                16, 0, 0);
        }
    };

    stage(0);
#pragma unroll 1
    for (int it = 0; it < 4; ++it) {
        const int l   = l0 + it;
        const int sidx = l % MAXSTEP;
        const int cur = it & 1;
        if (it < 3) {
            stage(it + 1);
            asm volatile("s_waitcnt vmcnt(8)" ::: "memory");
        } else {
            asm volatile("s_waitcnt vmcnt(0)" ::: "memory");
        }
        __builtin_amdgcn_s_barrier();
        __builtin_amdgcn_sched_barrier(0);

        f32x4 acc[2][4] = {};
        const float* Wf = W + (size_t)sidx * E_ * H_;
#pragma unroll 2
        for (int kk = 0; kk < 8; ++kk) {
            const int k0 = kk * 32;
            const int c0 = kk * 8 + g * 2;
            f32x4 a0lo = *(const f32x4*)&aLds[cur][r * 256 + ((c0 ^ key) << 2)];
            f32x4 a0hi = *(const f32x4*)&aLds[cur][r * 256 + (((c0 + 1) ^ key) << 2)];
            f32x4 a1lo = *(const f32x4*)&aLds[cur][(r + 16) * 256 + ((c0 ^ key) << 2)];
            f32x4 a1hi = *(const f32x4*)&aLds[cur][(r + 16) * 256 + (((c0 + 1) ^ key) << 2)];
            bf16x8 a0, a1;
#pragma unroll
            for (int j = 0; j < 4; ++j) {
                a0[j]     = cvt1(a0lo[j]);
                a0[j + 4] = cvt1(a0hi[j]);
                a1[j]     = cvt1(a1lo[j]);
                a1[j + 4] = cvt1(a1hi[j]);
            }
            bf16x8 b0, b1, b2, b3;
#pragma unroll
            for (int j = 0; j < 8; ++j) {
                const size_t krow = (size_t)(k0 + g * 8 + j) * H_;
                b0[j] = cvt1(Wf[krow + nbase +  0 + r]);
                b1[j] = cvt1(Wf[krow + nbase + 16 + r]);
                b2[j] = cvt1(Wf[krow + nbase + 32 + r]);
                b3[j] = cvt1(Wf[krow + nbase + 48 + r]);
            }
            acc[0][0] = __builtin_amdgcn_mfma_f32_16x16x32_bf16(a0, b0, acc[0][0], 0, 0, 0);
            acc[0][1] = __builtin_amdgcn_mfma_f32_16x16x32_bf16(a0, b1, acc[0][1], 0, 0, 0);
            acc[0][2] = __builtin_amdgcn_mfma_f32_16x16x32_bf16(a0, b2, acc[0][2], 0, 0, 0);
            acc[0][3] = __builtin_amdgcn_mfma_f32_16x16x32_bf16(a0, b3, acc[0][3], 0, 0, 0);
            acc[1][0] = __builtin_amdgcn_mfma_f32_16x16x32_bf16(a1, b0, acc[1][0], 0, 0, 0);
            acc[1][1] = __builtin_amdgcn_mfma_f32_16x16x32_bf16(a1, b1, acc[1][1], 0, 0, 0);
            acc[1][2] = __builtin_amdgcn_mfma_f32_16x16x32_bf16(a1, b2, acc[1][2], 0, 0, 0);
            acc[1][3] = __builtin_amdgcn_mfma_f32_16x16x32_bf16(a1, b3, acc[1][3], 0, 0, 0);
        }

        const int row0 = g * 4;
#pragma unroll
        for (int mf = 0; mf < 2; ++mf)
#pragma unroll
            for (int nf = 0; nf < 4; ++nf) {
                const int h = nbase + nf * 16 + r;
#pragma unroll
                for (int i = 0; i < 4; ++i) {
                    const int bb = mf * 16 + row0 + i;
                    out[((size_t)bb * L_ + l) * H_ + h] = acc[mf][nf][i];
                }
            }
        if (l == L_ - 1) {
            float* out2 = out + (size_t)B_ * L_ * H_;
#pragma unroll
            for (int mf = 0; mf < 2; ++mf)
#pragma unroll
                for (int nf = 0; nf < 4; ++nf) {
                    const int h = nbase + nf * 16 + r;
#pragma unroll
                    for (int i = 0; i < 4; ++i) {
                        const int bb = mf * 16 + row0 + i;
                        out2[(size_t)bb * H_ + h] = acc[mf][nf][i];
                    }
                }
        }
        __builtin_amdgcn_s_barrier();
    }
}

extern "C" void kernel_launch(void* const* d_in, const int* in_sizes, int n_in,
                              void* d_out, int out_size, void* d_ws, size_t ws_size,
                              hipStream_t stream) {
    const float* word_rep = (const float*)d_in[0];
    const float* cnn      = (const float*)d_in[1];
    float* out = (float*)d_out;

    const size_t wt_bytes = (size_t)MAXSTEP * E_ * H_ * sizeof(short);
    if (ws_size >= wt_bytes) {
        short* wt = (short*)d_ws;
        transpose_w_kernel<<<dim3(8, 8, 20), dim3(32, 8), 0, stream>>>(cnn, wt);
        vaw_wave_kernel<<<dim3(NGRP * 4), dim3(64), 0, stream>>>(word_rep, wt, out);
    } else {
        vaw_fallback_kernel<<<dim3(L_ / 4), dim3(256), 0, stream>>>(word_rep, cnn, out);
    }
}